// Round 1
// baseline (1488.236 us; speedup 1.0000x reference)
//
#include <hip/hip_runtime.h>

// ---------------- problem constants ----------------
constexpr int B_ = 256;        // batch
constexpr int K_ = 6144;       // block length
constexpr int NITER = 6;
constexpr int L_ = 128;        // window valid length
constexpr int W_ = 128;        // warmup length
constexpr int C_ = K_ / L_;    // chunks = 48
constexpr float NEGF = -1e30f;
constexpr float LOG2E = 1.4426950408889634f;
constexpr float LN2   = 0.6931471805599453f;

static_assert(K_ % L_ == 0, "");
static_assert((L_ % 4) == 0 && (W_ % 4) == 0, "");

// ---------------- trellis (derived from G0=(1,0,1,1), G1=(1,1,0,1), MU=3) ----
// fb(s,u)  = u ^ s1 ^ s0
// nxt(s,u) = (fb<<2) | (s>>1)
// par(s,u) = u ^ s1 ^ s2
// gamma(s,u) = (u? -hs : hs) + (par? -hp : hp),  hs=0.5*lsu', hp=0.5*lp'
// fwd predecessors of sn: p_i = ((sn&3)<<1)|i,
//   u_i  = (sn>>2)^(sn&1)^i,   par_i = (sn>>2)^((sn>>1)&1)^i

__device__ __forceinline__ float jac2(float x, float y) {
  float m = fmaxf(x, y);
  float d = -fabsf(x - y);
  return m + log2f(1.0f + exp2f(d));   // log2-domain Jacobian logsumexp
}

__device__ __forceinline__ void mk_gt(float2 gv, float gt[2][2]) {
  float hs = 0.5f * gv.x, hp = 0.5f * gv.y;
  gt[0][0] = hs + hp;
  gt[0][1] = hs - hp;
  gt[1][0] = -(hs - hp);
  gt[1][1] = -(hs + hp);
}

__device__ __forceinline__ void step_fwd(float a[8], float2 gv) {
  float gt[2][2];
  mk_gt(gv, gt);
  float an[8];
#pragma unroll
  for (int sn = 0; sn < 8; ++sn) {
    const int u0 = ((sn >> 2) ^ (sn & 1)) & 1;
    const int p0 = ((sn >> 2) ^ ((sn >> 1) & 1)) & 1;
    float x0 = a[(sn & 3) * 2 + 0] + gt[u0][p0];
    float x1 = a[(sn & 3) * 2 + 1] + gt[u0 ^ 1][p0 ^ 1];
    an[sn] = jac2(x0, x1);
  }
#pragma unroll
  for (int s = 0; s < 8; ++s) a[s] = an[s];
}

__device__ __forceinline__ void step_bwd(float a[8], float2 gv) {
  float gt[2][2];
  mk_gt(gv, gt);
  float an[8];
#pragma unroll
  for (int s = 0; s < 8; ++s) {
    const int s0 = s & 1, s1b = (s >> 1) & 1, s2b = (s >> 2) & 1;
    const int f0 = s1b ^ s0;
    float x0 = a[(f0 << 2) | (s >> 1)]       + gt[0][s1b ^ s2b];
    float x1 = a[((f0 ^ 1) << 2) | (s >> 1)] + gt[1][(s1b ^ s2b) ^ 1];
    an[s] = jac2(x0, x1);
  }
#pragma unroll
  for (int s = 0; s < 8; ++s) a[s] = an[s];
}

__device__ __forceinline__ void renorm(float a[8]) {
  float m = a[0];
#pragma unroll
  for (int s = 1; s < 8; ++s) a[s] -= m;
  a[0] = 0.0f;
}

// ---------------- k_state: windowed fwd/bwd recursions --------------------
// grid: 2*C_*4 blocks of 64 threads. block -> (b-quarter, dir, chunk)
__global__ __launch_bounds__(64) void k_state(const float2* __restrict__ g,
                                              float* __restrict__ alphas,
                                              float* __restrict__ betas) {
  const int tid = threadIdx.x;
  const unsigned wg = blockIdx.x;
  const int b = (int)(wg & 3u) * 64 + tid;
  const unsigned r2 = wg >> 2;
  const int dir = (int)(r2 & 1u);
  const int c = (int)(r2 >> 1);
  const int kv = c * L_;
  float a[8];

  if (dir == 0) {
    // -------- forward --------
    if (c == 0) {
      a[0] = 0.0f;
#pragma unroll
      for (int s = 1; s < 8; ++s) a[s] = NEGF;
    } else {
#pragma unroll
      for (int s = 0; s < 8; ++s) a[s] = 0.0f;
    }
    int k = kv - ((c == 0) ? 0 : W_);
    for (int n = ((c == 0) ? 0 : W_); n > 0; n -= 4) {
#pragma unroll
      for (int q = 0; q < 4; ++q) {
        float2 gv = g[(size_t)(k + q) * B_ + b];
        step_fwd(a, gv);
      }
      renorm(a);
      k += 4;
    }
    for (int n = L_; n > 0; n -= 4) {
#pragma unroll
      for (int q = 0; q < 4; ++q) {
        float2 gv = g[(size_t)(k + q) * B_ + b];
#pragma unroll
        for (int s = 0; s < 8; ++s)
          alphas[((size_t)(k + q) * 8 + s) * B_ + b] = a[s];
        step_fwd(a, gv);
      }
      renorm(a);
      k += 4;
    }
  } else {
    // -------- backward -------- (stores beta_{k+1} at slot k)
#pragma unroll
    for (int s = 0; s < 8; ++s) a[s] = 0.0f;
    const int wu = (c == C_ - 1) ? 0 : W_;
    int k = kv + L_ - 1 + wu;
    for (int n = wu; n > 0; n -= 4) {
#pragma unroll
      for (int q = 0; q < 4; ++q) {
        float2 gv = g[(size_t)(k - q) * B_ + b];
        step_bwd(a, gv);
      }
      renorm(a);
      k -= 4;
    }
    for (int n = L_; n > 0; n -= 4) {
#pragma unroll
      for (int q = 0; q < 4; ++q) {
        float2 gv = g[(size_t)(k - q) * B_ + b];
#pragma unroll
        for (int s = 0; s < 8; ++s)
          betas[((size_t)(k - q) * 8 + s) * B_ + b] = a[s];
        step_bwd(a, gv);
      }
      renorm(a);
      k -= 4;
    }
  }
}

// ---------------- k_comb: posterior + extrinsic + interleave --------------
// block p over K, 256 threads = b. Reads row p of alphas/betas/gin;
// writes row map[p] of gout (gout.x = ls_other + extrinsic, keeps .y).
__global__ __launch_bounds__(256) void k_comb(const float* __restrict__ alphas,
                                              const float* __restrict__ betas,
                                              const float2* __restrict__ gin,
                                              const float* __restrict__ lsother,
                                              const int* __restrict__ map,
                                              float2* __restrict__ gout,
                                              float* __restrict__ lpost_out,
                                              int writeLpost) {
  const int b = threadIdx.x;
  const int p = blockIdx.x;
  float al[8], be[8];
#pragma unroll
  for (int s = 0; s < 8; ++s) {
    al[s] = alphas[((size_t)p * 8 + s) * B_ + b];
    be[s] = betas[((size_t)p * 8 + s) * B_ + b];
  }
  float2 gv = gin[(size_t)p * B_ + b];
  float gt[2][2];
  mk_gt(gv, gt);
  float t0[8], t1[8];
#pragma unroll
  for (int s = 0; s < 8; ++s) {
    const int s0 = s & 1, s1b = (s >> 1) & 1, s2b = (s >> 2) & 1;
    const int f0 = s1b ^ s0;
    float base = al[s];
    t0[s] = base + gt[0][s1b ^ s2b]       + be[(f0 << 2) | (s >> 1)];
    t1[s] = base + gt[1][(s1b ^ s2b) ^ 1] + be[((f0 ^ 1) << 2) | (s >> 1)];
  }
  float e0 = jac2(jac2(jac2(t0[0], t0[1]), jac2(t0[2], t0[3])),
                  jac2(jac2(t0[4], t0[5]), jac2(t0[6], t0[7])));
  float e1 = jac2(jac2(jac2(t1[0], t1[1]), jac2(t1[2], t1[3])),
                  jac2(jac2(t1[4], t1[5]), jac2(t1[6], t1[7])));
  float lpost = e0 - e1;
  float le = lpost - gv.x;               // lpost - (ls + la)
  const int j = map[p];
  const size_t o = (size_t)j * B_ + b;
  float2 outv;
  outv.x = lsother[o] + le;
  outv.y = gout[o].y;                    // keep parity LLR of target code
  gout[o] = outv;
  if (writeLpost) lpost_out[(size_t)p * B_ + b] = lpost;
}

// ---------------- prep: de-interleave + transpose + scale to log2 domain --
__global__ __launch_bounds__(256) void k_prep1(const float* __restrict__ inp,
                                               float* __restrict__ ls1,
                                               float2* __restrict__ g1,
                                               float2* __restrict__ g2) {
  __shared__ float t[3][64][65];
  const int tid = threadIdx.x;
  const int k0 = blockIdx.x * 64, b0 = blockIdx.y * 64;
  const int tk = tid & 63, tq = tid >> 6;
  for (int bb = tq; bb < 64; bb += 4) {
    size_t base = (size_t)(b0 + bb) * (3 * K_) + 3 * (size_t)(k0 + tk);
    t[0][bb][tk] = inp[base + 0];
    t[1][bb][tk] = inp[base + 1];
    t[2][bb][tk] = inp[base + 2];
  }
  __syncthreads();
  const int tb = tid & 63, kq = tid >> 6;
  for (int kk = kq; kk < 64; kk += 4) {
    size_t o = (size_t)(k0 + kk) * B_ + (b0 + tb);
    float sv = -LOG2E * t[0][tb][kk];
    float p1 = -LOG2E * t[1][tb][kk];
    float p2 = -LOG2E * t[2][tb][kk];
    ls1[o] = sv;
    g1[o] = make_float2(sv, p1);   // la=0 initially -> lsu = ls
    g2[o] = make_float2(0.0f, p2); // .x overwritten by k_comb before use
  }
}

__global__ __launch_bounds__(256) void k_prep2(const float* __restrict__ ls1,
                                               const int* __restrict__ perm,
                                               float* __restrict__ ls2,
                                               int* __restrict__ inv) {
  const int j = blockIdx.x;
  const int b = threadIdx.x;
  const int p = perm[j];
  ls2[(size_t)j * B_ + b] = ls1[(size_t)p * B_ + b];
  if (b == 0) inv[p] = j;
}

// ---------------- output: out[b,i] = -ln2 * lpost2'[inv[i], b] ------------
__global__ __launch_bounds__(256) void k_out(const float* __restrict__ lpost2t,
                                             const int* __restrict__ inv,
                                             float* __restrict__ out) {
  __shared__ float t[64][65];
  const int tid = threadIdx.x;
  const int i0 = blockIdx.x * 64, b0 = blockIdx.y * 64;
  const int tb = tid & 63, iq = tid >> 6;
  for (int ii = iq; ii < 64; ii += 4) {
    int row = inv[i0 + ii];
    t[ii][tb] = lpost2t[(size_t)row * B_ + (b0 + tb)];
  }
  __syncthreads();
  const int ik = tid & 63, bq = tid >> 6;
  for (int bb = bq; bb < 64; bb += 4) {
    out[(size_t)(b0 + bb) * K_ + (i0 + ik)] = -LN2 * t[ik][bb];
  }
}

// ---------------- launch ---------------------------------------------------
extern "C" void kernel_launch(void* const* d_in, const int* in_sizes, int n_in,
                              void* d_out, int out_size, void* d_ws, size_t ws_size,
                              hipStream_t stream) {
  (void)in_sizes; (void)n_in; (void)out_size; (void)ws_size;
  const float* inp = (const float*)d_in[0];
  const int* perm = (const int*)d_in[1];
  float* out = (float*)d_out;

  char* ws = (char*)d_ws;
  const size_t KB = (size_t)K_ * B_;   // elements per [K][B] plane
  float2* g1      = (float2*)(ws);              // KB float2  (lsu1, lp1)
  float2* g2      = (float2*)(ws + KB * 8);     // KB float2  (lsu2, lp2)
  float*  ls1     = (float*)(ws + KB * 16);     // KB f32
  float*  ls2     = (float*)(ws + KB * 20);     // KB f32
  float*  alphas  = (float*)(ws + KB * 24);     // 8*KB f32
  float*  betas   = (float*)(ws + KB * 56);     // 8*KB f32
  float*  lpost2t = (float*)(ws + KB * 88);     // KB f32
  int*    inv     = (int*)(ws + KB * 92);       // K ints
  // total: KB*92 + 4K bytes  ~= 144.7 MB

  k_prep1<<<dim3(K_ / 64, B_ / 64), 256, 0, stream>>>(inp, ls1, g1, g2);
  k_prep2<<<K_, 256, 0, stream>>>(ls1, perm, ls2, inv);

  for (int it = 0; it < NITER; ++it) {
    k_state<<<2 * C_ * 4, 64, 0, stream>>>(g1, alphas, betas);
    k_comb<<<K_, 256, 0, stream>>>(alphas, betas, g1, ls2, inv, g2, lpost2t, 0);
    k_state<<<2 * C_ * 4, 64, 0, stream>>>(g2, alphas, betas);
    k_comb<<<K_, 256, 0, stream>>>(alphas, betas, g2, ls1, perm, g1, lpost2t,
                                   (it == NITER - 1) ? 1 : 0);
  }
  k_out<<<dim3(K_ / 64, B_ / 64), 256, 0, stream>>>(lpost2t, inv, out);
}

// Round 2
// 790.881 us; speedup vs baseline: 1.8817x; 1.8817x over previous
//
#include <hip/hip_runtime.h>

// ---------------- problem constants ----------------
constexpr int B_ = 256;        // batch
constexpr int K_ = 6144;       // block length
constexpr int NITER = 6;
constexpr int L_ = 16;         // window valid length
constexpr int W_ = 48;         // warmup length (16 constraint lengths)
constexpr int C_ = K_ / L_;    // chunks = 384
constexpr float NEGF = -1e30f;
constexpr float LOG2E = 1.4426950408889634f;
constexpr float LN2   = 0.6931471805599453f;

static_assert(K_ % L_ == 0, "");
static_assert((L_ % 4) == 0 && (W_ % 4) == 0 && (W_ % L_ == 0), "");

#if __has_builtin(__builtin_amdgcn_exp2f)
#define EXP2F(x) __builtin_amdgcn_exp2f(x)
#else
#define EXP2F(x) exp2f(x)
#endif
#if __has_builtin(__builtin_amdgcn_logf)
#define LOG2F(x) __builtin_amdgcn_logf(x)
#else
#define LOG2F(x) log2f(x)
#endif

// trellis: fb(s,u)=u^s1^s0, nxt(s,u)=(fb<<2)|(s>>1), par(s,u)=u^s1^s2
// gamma in log2 domain: gt[u][p] built from hs=0.5*lsu', hp=0.5*lp'

__device__ __forceinline__ float jac2(float x, float y) {
  float m = fmaxf(x, y);
  float d = -fabsf(x - y);
  return m + LOG2F(1.0f + EXP2F(d));   // log2-domain Jacobian logsumexp
}

__device__ __forceinline__ void mk_gt(float gx, float gy, float gt[2][2]) {
  float hs = 0.5f * gx, hp = 0.5f * gy;
  gt[0][0] = hs + hp;
  gt[0][1] = hs - hp;
  gt[1][0] = -(hs - hp);
  gt[1][1] = -(hs + hp);
}

__device__ __forceinline__ void step_fwd(float a[8], float gx, float gy) {
  float gt[2][2];
  mk_gt(gx, gy, gt);
  float an[8];
#pragma unroll
  for (int sn = 0; sn < 8; ++sn) {
    const int u0 = ((sn >> 2) ^ (sn & 1)) & 1;
    const int p0 = ((sn >> 2) ^ ((sn >> 1) & 1)) & 1;
    float x0 = a[(sn & 3) * 2 + 0] + gt[u0][p0];
    float x1 = a[(sn & 3) * 2 + 1] + gt[u0 ^ 1][p0 ^ 1];
    an[sn] = jac2(x0, x1);
  }
#pragma unroll
  for (int s = 0; s < 8; ++s) a[s] = an[s];
}

__device__ __forceinline__ void step_bwd(float a[8], float gx, float gy) {
  float gt[2][2];
  mk_gt(gx, gy, gt);
  float an[8];
#pragma unroll
  for (int s = 0; s < 8; ++s) {
    const int s0 = s & 1, s1b = (s >> 1) & 1, s2b = (s >> 2) & 1;
    const int f0 = s1b ^ s0;
    float x0 = a[(f0 << 2) | (s >> 1)]       + gt[0][s1b ^ s2b];
    float x1 = a[((f0 ^ 1) << 2) | (s >> 1)] + gt[1][(s1b ^ s2b) ^ 1];
    an[s] = jac2(x0, x1);
  }
#pragma unroll
  for (int s = 0; s < 8; ++s) a[s] = an[s];
}

__device__ __forceinline__ void renorm(float a[8]) {
  float m = a[0];
#pragma unroll
  for (int s = 1; s < 8; ++s) a[s] -= m;
  a[0] = 0.0f;
}

// ---------------- k_fwd: windowed forward recursion, stores alpha ---------
// grid: C_*4 blocks of 64. block -> (b-quarter, chunk). alpha layout [K][B][8].
__global__ __launch_bounds__(64) void k_fwd(const float* __restrict__ gx,
                                            const float* __restrict__ gy,
                                            float4* __restrict__ alphas4) {
  const int tid = threadIdx.x;
  const unsigned wg = blockIdx.x;
  const int b = (int)(wg & 3u) * 64 + tid;
  const int c = (int)(wg >> 2);
  const int kv = c * L_;
  float a[8];

  int k0 = kv - W_;
  if (k0 <= 0) {
    k0 = 0;                       // exact init at trellis start
    a[0] = 0.0f;
#pragma unroll
    for (int s = 1; s < 8; ++s) a[s] = NEGF;
  } else {
#pragma unroll
    for (int s = 0; s < 8; ++s) a[s] = 0.0f;   // uniform init
  }
  int k = k0;
  for (int n = kv - k0; n > 0; n -= 4) {
#pragma unroll
    for (int q = 0; q < 4; ++q) {
      size_t o = (size_t)(k + q) * B_ + b;
      step_fwd(a, gx[o], gy[o]);
    }
    renorm(a);
    k += 4;
  }
  for (int n = L_; n > 0; n -= 4) {
#pragma unroll
    for (int q = 0; q < 4; ++q) {
      size_t o = (size_t)(k + q) * B_ + b;
      float4* ap = alphas4 + o * 2;
      ap[0] = make_float4(a[0], a[1], a[2], a[3]);
      ap[1] = make_float4(a[4], a[5], a[6], a[7]);
      step_fwd(a, gx[o], gy[o]);
    }
    renorm(a);
    k += 4;
  }
}

// ---------------- k_bwd: windowed backward recursion + fused posterior ----
// For each valid position: compute x0/x1 (shared by beta step and posterior),
// emit extrinsic scatter-write into the other decoder's gx plane.
__global__ __launch_bounds__(64) void k_bwd(const float* __restrict__ gx,
                                            const float* __restrict__ gy,
                                            const float4* __restrict__ alphas4,
                                            const float* __restrict__ lsother,
                                            const int* __restrict__ map,
                                            float* __restrict__ gxother,
                                            float* __restrict__ lpost_out,
                                            int writeLpost) {
  const int tid = threadIdx.x;
  const unsigned wg = blockIdx.x;
  const int b = (int)(wg & 3u) * 64 + tid;
  const int c = (int)(wg >> 2);
  const int kv = c * L_;
  const int kend = kv + L_;
  float bt[8];
#pragma unroll
  for (int s = 0; s < 8; ++s) bt[s] = 0.0f;    // uniform == exact tail init

  int wu = K_ - kend;
  if (wu > W_) wu = W_;
  int k = kend + wu - 1;
  for (int n = wu; n > 0; n -= 4) {
#pragma unroll
    for (int q = 0; q < 4; ++q) {
      size_t o = (size_t)(k - q) * B_ + b;
      step_bwd(bt, gx[o], gy[o]);
    }
    renorm(bt);
    k -= 4;
  }
  // k == kend-1, bt holds beta_{k+1}
  for (int n = L_; n > 0; n -= 4) {
#pragma unroll
    for (int q = 0; q < 4; ++q) {
      const int kk = k - q;
      size_t o = (size_t)kk * B_ + b;
      float gvx = gx[o], gvy = gy[o];
      float gt[2][2];
      mk_gt(gvx, gvy, gt);
      float x0[8], x1[8];
#pragma unroll
      for (int s = 0; s < 8; ++s) {
        const int s0 = s & 1, s1b = (s >> 1) & 1, s2b = (s >> 2) & 1;
        const int f0 = s1b ^ s0;
        const int p0 = s1b ^ s2b;
        x0[s] = bt[(f0 << 2) | (s >> 1)]       + gt[0][p0];
        x1[s] = bt[((f0 ^ 1) << 2) | (s >> 1)] + gt[1][p0 ^ 1];
      }
      const float4* ap = alphas4 + o * 2;
      float4 a03 = ap[0], a47 = ap[1];
      float al[8] = {a03.x, a03.y, a03.z, a03.w, a47.x, a47.y, a47.z, a47.w};
      float t0[8], t1[8];
#pragma unroll
      for (int s = 0; s < 8; ++s) {
        t0[s] = al[s] + x0[s];
        t1[s] = al[s] + x1[s];
      }
      float e0 = jac2(jac2(jac2(t0[0], t0[1]), jac2(t0[2], t0[3])),
                      jac2(jac2(t0[4], t0[5]), jac2(t0[6], t0[7])));
      float e1 = jac2(jac2(jac2(t1[0], t1[1]), jac2(t1[2], t1[3])),
                      jac2(jac2(t1[4], t1[5]), jac2(t1[6], t1[7])));
      float lpost = e0 - e1;
      float le = lpost - gvx;                  // lpost - (ls + la)
      const int j = map[kk];
      const size_t oo = (size_t)j * B_ + b;
      gxother[oo] = lsother[oo] + le;
      if (writeLpost) lpost_out[o] = lpost;
      // beta step (shares x0/x1)
#pragma unroll
      for (int s = 0; s < 8; ++s) bt[s] = jac2(x0[s], x1[s]);
    }
    renorm(bt);
    k -= 4;
  }
}

// ---------------- prep: de-interleave + transpose + scale to log2 domain --
__global__ __launch_bounds__(256) void k_prep1(const float* __restrict__ inp,
                                               float* __restrict__ ls1,
                                               float* __restrict__ gx1,
                                               float* __restrict__ gy1,
                                               float* __restrict__ gy2) {
  __shared__ float t[3][64][65];
  const int tid = threadIdx.x;
  const int k0 = blockIdx.x * 64, b0 = blockIdx.y * 64;
  const int tk = tid & 63, tq = tid >> 6;
  for (int bb = tq; bb < 64; bb += 4) {
    size_t base = (size_t)(b0 + bb) * (3 * K_) + 3 * (size_t)(k0 + tk);
    t[0][bb][tk] = inp[base + 0];
    t[1][bb][tk] = inp[base + 1];
    t[2][bb][tk] = inp[base + 2];
  }
  __syncthreads();
  const int tb = tid & 63, kq = tid >> 6;
  for (int kk = kq; kk < 64; kk += 4) {
    size_t o = (size_t)(k0 + kk) * B_ + (b0 + tb);
    float sv = -LOG2E * t[0][tb][kk];
    float p1 = -LOG2E * t[1][tb][kk];
    float p2 = -LOG2E * t[2][tb][kk];
    ls1[o] = sv;
    gx1[o] = sv;          // la=0 initially -> lsu = ls
    gy1[o] = p1;
    gy2[o] = p2;
  }
}

__global__ __launch_bounds__(256) void k_prep2(const float* __restrict__ ls1,
                                               const int* __restrict__ perm,
                                               float* __restrict__ ls2,
                                               int* __restrict__ inv) {
  const int j = blockIdx.x;
  const int b = threadIdx.x;
  const int p = perm[j];
  ls2[(size_t)j * B_ + b] = ls1[(size_t)p * B_ + b];
  if (b == 0) inv[p] = j;
}

// ---------------- output: out[b,i] = -ln2 * lpost2'[inv[i], b] ------------
__global__ __launch_bounds__(256) void k_out(const float* __restrict__ lpost2t,
                                             const int* __restrict__ inv,
                                             float* __restrict__ out) {
  __shared__ float t[64][65];
  const int tid = threadIdx.x;
  const int i0 = blockIdx.x * 64, b0 = blockIdx.y * 64;
  const int tb = tid & 63, iq = tid >> 6;
  for (int ii = iq; ii < 64; ii += 4) {
    int row = inv[i0 + ii];
    t[ii][tb] = lpost2t[(size_t)row * B_ + (b0 + tb)];
  }
  __syncthreads();
  const int ik = tid & 63, bq = tid >> 6;
  for (int bb = bq; bb < 64; bb += 4) {
    out[(size_t)(b0 + bb) * K_ + (i0 + ik)] = -LN2 * t[ik][bb];
  }
}

// ---------------- launch ---------------------------------------------------
extern "C" void kernel_launch(void* const* d_in, const int* in_sizes, int n_in,
                              void* d_out, int out_size, void* d_ws, size_t ws_size,
                              hipStream_t stream) {
  (void)in_sizes; (void)n_in; (void)out_size; (void)ws_size;
  const float* inp = (const float*)d_in[0];
  const int* perm = (const int*)d_in[1];
  float* out = (float*)d_out;

  char* ws = (char*)d_ws;
  const size_t KB = (size_t)K_ * B_;     // elements per [K][B] plane
  const size_t PB = KB * 4;              // bytes per f32 plane
  float*  gx1     = (float*)(ws);
  float*  gy1     = (float*)(ws + PB);
  float*  gx2     = (float*)(ws + PB * 2);
  float*  gy2     = (float*)(ws + PB * 3);
  float*  ls1     = (float*)(ws + PB * 4);
  float*  ls2     = (float*)(ws + PB * 5);
  float4* alphas4 = (float4*)(ws + PB * 6);     // [K][B][8] f32 = 8 planes
  float*  lpost2t = (float*)(ws + PB * 14);
  int*    inv     = (int*)(ws + PB * 15);       // K ints
  // total: 15 planes * 6 MB + 24 KB ~= 94.4 MB

  k_prep1<<<dim3(K_ / 64, B_ / 64), 256, 0, stream>>>(inp, ls1, gx1, gy1, gy2);
  k_prep2<<<K_, 256, 0, stream>>>(ls1, perm, ls2, inv);

  for (int it = 0; it < NITER; ++it) {
    k_fwd<<<C_ * 4, 64, 0, stream>>>(gx1, gy1, alphas4);
    k_bwd<<<C_ * 4, 64, 0, stream>>>(gx1, gy1, alphas4, ls2, inv, gx2,
                                     lpost2t, 0);
    k_fwd<<<C_ * 4, 64, 0, stream>>>(gx2, gy2, alphas4);
    k_bwd<<<C_ * 4, 64, 0, stream>>>(gx2, gy2, alphas4, ls1, perm, gx1,
                                     lpost2t, (it == NITER - 1) ? 1 : 0);
  }
  k_out<<<dim3(K_ / 64, B_ / 64), 256, 0, stream>>>(lpost2t, inv, out);
}

// Round 3
// 638.899 us; speedup vs baseline: 2.3294x; 1.2379x over previous
//
#include <hip/hip_runtime.h>

// ---------------- problem constants ----------------
constexpr int B_ = 256;        // batch
constexpr int K_ = 6144;       // block length
constexpr int NITER = 6;
constexpr int L_ = 16;         // window valid length (also reg-array size)
constexpr int W_ = 32;         // warmup length (~10.7 constraint lengths)
constexpr int C_ = K_ / L_;    // chunks = 384
constexpr float NEGF = -1e30f;
constexpr float LOG2E = 1.4426950408889634f;
constexpr float LN2   = 0.6931471805599453f;

static_assert(K_ % L_ == 0, "");
static_assert((L_ % 4) == 0 && (W_ % 4) == 0, "");

#if __has_builtin(__builtin_amdgcn_exp2f)
#define EXP2F(x) __builtin_amdgcn_exp2f(x)
#else
#define EXP2F(x) exp2f(x)
#endif
#if __has_builtin(__builtin_amdgcn_logf)
#define LOG2F(x) __builtin_amdgcn_logf(x)
#else
#define LOG2F(x) log2f(x)
#endif

// trellis: fb(s,u)=u^s1^s0, nxt(s,u)=(fb<<2)|(s>>1), par(s,u)=u^s1^s2
// log2-domain gamma: gt[u][p] from hs=0.5*lsu', hp=0.5*lp'

__device__ __forceinline__ float jac2(float x, float y) {
  float m = fmaxf(x, y);
  float d = -fabsf(x - y);
  return m + LOG2F(1.0f + EXP2F(d));   // log2-domain Jacobian logsumexp
}

__device__ __forceinline__ void mk_gt(float gx, float gy, float gt[2][2]) {
  float hs = 0.5f * gx, hp = 0.5f * gy;
  gt[0][0] = hs + hp;
  gt[0][1] = hs - hp;
  gt[1][0] = -(hs - hp);
  gt[1][1] = -(hs + hp);
}

__device__ __forceinline__ void step_fwd(float a[8], float gx, float gy) {
  float gt[2][2];
  mk_gt(gx, gy, gt);
  float an[8];
#pragma unroll
  for (int sn = 0; sn < 8; ++sn) {
    const int u0 = ((sn >> 2) ^ (sn & 1)) & 1;
    const int p0 = ((sn >> 2) ^ ((sn >> 1) & 1)) & 1;
    float x0 = a[(sn & 3) * 2 + 0] + gt[u0][p0];
    float x1 = a[(sn & 3) * 2 + 1] + gt[u0 ^ 1][p0 ^ 1];
    an[sn] = jac2(x0, x1);
  }
#pragma unroll
  for (int s = 0; s < 8; ++s) a[s] = an[s];
}

__device__ __forceinline__ void step_bwd(float a[8], float gx, float gy) {
  float gt[2][2];
  mk_gt(gx, gy, gt);
  float an[8];
#pragma unroll
  for (int s = 0; s < 8; ++s) {
    const int s0 = s & 1, s1b = (s >> 1) & 1, s2b = (s >> 2) & 1;
    const int f0 = s1b ^ s0;
    float x0 = a[(f0 << 2) | (s >> 1)]       + gt[0][s1b ^ s2b];
    float x1 = a[((f0 ^ 1) << 2) | (s >> 1)] + gt[1][(s1b ^ s2b) ^ 1];
    an[s] = jac2(x0, x1);
  }
#pragma unroll
  for (int s = 0; s < 8; ++s) a[s] = an[s];
}

__device__ __forceinline__ void renorm(float a[8]) {
  float m = a[0];
#pragma unroll
  for (int s = 1; s < 8; ++s) a[s] -= m;
  a[0] = 0.0f;
}

// ---------------- k_half: one full windowed BCJR half-iteration -----------
// One wave per (b-quarter, chunk). alpha for the L valid positions lives in
// registers (16x8 f32); gamma of the valid region cached in registers too.
// mode 0: scatter extrinsic into other decoder's gx.  mode 1: write lpost.
__global__ __launch_bounds__(64, 2) void k_half(const float* __restrict__ gx,
                                                const float* __restrict__ gy,
                                                const float* __restrict__ lsother,
                                                const int* __restrict__ map,
                                                float* __restrict__ gxother,
                                                float* __restrict__ lpost_out,
                                                int mode) {
  const int tid = threadIdx.x;
  const unsigned wg = blockIdx.x;
  const int b = (int)(wg & 3u) * 64 + tid;
  const int c = (int)(wg >> 2);
  const int kv = c * L_;
  const int kend = kv + L_;

  // prefetch valid-region gamma (in flight during fwd warmup)
  float gvx[L_], gvy[L_];
#pragma unroll
  for (int i = 0; i < L_; ++i) {
    size_t o = (size_t)(kv + i) * B_ + b;
    gvx[i] = gx[o];
    gvy[i] = gy[o];
  }

  // ---------------- forward ----------------
  float a[8];
  int k0 = kv - W_;
  if (k0 < 0) k0 = 0;
  if (c == 0) {
    a[0] = 0.0f;
#pragma unroll
    for (int s = 1; s < 8; ++s) a[s] = NEGF;
  } else {
#pragma unroll
    for (int s = 0; s < 8; ++s) a[s] = 0.0f;
  }
  {
    int n = kv - k0;     // multiple of 16 (0, 16, or 32)
    int k = k0;
    float cx[4], cy[4];
    if (n > 0) {
#pragma unroll
      for (int q = 0; q < 4; ++q) {
        size_t o = (size_t)(k + q) * B_ + b;
        cx[q] = gx[o]; cy[q] = gy[o];
      }
    }
    while (n > 0) {
      float nx[4], ny[4];
      if (n > 4) {
#pragma unroll
        for (int q = 0; q < 4; ++q) {
          size_t o = (size_t)(k + 4 + q) * B_ + b;
          nx[q] = gx[o]; ny[q] = gy[o];
        }
      }
#pragma unroll
      for (int q = 0; q < 4; ++q) step_fwd(a, cx[q], cy[q]);
      renorm(a);
      if (n > 4) {
#pragma unroll
        for (int q = 0; q < 4; ++q) { cx[q] = nx[q]; cy[q] = ny[q]; }
      }
      k += 4; n -= 4;
    }
  }
  // valid region: record alpha, then step
  float a2d[L_][8];
#pragma unroll
  for (int i = 0; i < L_; ++i) {
#pragma unroll
    for (int s = 0; s < 8; ++s) a2d[i][s] = a[s];
    if (i < L_ - 1) {
      step_fwd(a, gvx[i], gvy[i]);
      if ((i & 3) == 3) renorm(a);
    }
  }

  // ---------------- backward + posterior ----------------
  float bt[8];
#pragma unroll
  for (int s = 0; s < 8; ++s) bt[s] = 0.0f;   // uniform == exact tail init
  {
    int wu = K_ - kend;
    if (wu > W_) wu = W_;
    int n = wu;                                // multiple of 16
    int k = kend + wu - 1;
    float cx[4], cy[4];
    if (n > 0) {
#pragma unroll
      for (int q = 0; q < 4; ++q) {
        size_t o = (size_t)(k - q) * B_ + b;
        cx[q] = gx[o]; cy[q] = gy[o];
      }
    }
    while (n > 0) {
      float nx[4], ny[4];
      if (n > 4) {
#pragma unroll
        for (int q = 0; q < 4; ++q) {
          size_t o = (size_t)(k - 4 - q) * B_ + b;
          nx[q] = gx[o]; ny[q] = gy[o];
        }
      }
#pragma unroll
      for (int q = 0; q < 4; ++q) step_bwd(bt, cx[q], cy[q]);
      renorm(bt);
      if (n > 4) {
#pragma unroll
        for (int q = 0; q < 4; ++q) { cx[q] = nx[q]; cy[q] = ny[q]; }
      }
      k -= 4; n -= 4;
    }
  }
  // valid region, descending: posterior + extrinsic + beta step
#pragma unroll
  for (int ii = 0; ii < L_; ++ii) {
    const int i = L_ - 1 - ii;
    const int kk = kv + i;
    float gt[2][2];
    mk_gt(gvx[i], gvy[i], gt);
    float x0[8], x1[8];
#pragma unroll
    for (int s = 0; s < 8; ++s) {
      const int s0 = s & 1, s1b = (s >> 1) & 1, s2b = (s >> 2) & 1;
      const int f0 = s1b ^ s0;
      const int p0 = s1b ^ s2b;
      x0[s] = bt[(f0 << 2) | (s >> 1)]       + gt[0][p0];
      x1[s] = bt[((f0 ^ 1) << 2) | (s >> 1)] + gt[1][p0 ^ 1];
    }
    float t0[8], t1[8];
#pragma unroll
    for (int s = 0; s < 8; ++s) {
      t0[s] = a2d[i][s] + x0[s];
      t1[s] = a2d[i][s] + x1[s];
    }
    float e0 = jac2(jac2(jac2(t0[0], t0[1]), jac2(t0[2], t0[3])),
                    jac2(jac2(t0[4], t0[5]), jac2(t0[6], t0[7])));
    float e1 = jac2(jac2(jac2(t1[0], t1[1]), jac2(t1[2], t1[3])),
                    jac2(jac2(t1[4], t1[5]), jac2(t1[6], t1[7])));
    float lpost = e0 - e1;
    if (mode == 0) {
      float le = lpost - gvx[i];               // lpost - (ls + la)
      const int j = map[kk];
      const size_t oo = (size_t)j * B_ + b;
      gxother[oo] = lsother[oo] + le;
    } else {
      lpost_out[(size_t)kk * B_ + b] = lpost;
    }
    if (ii < L_ - 1) {
#pragma unroll
      for (int s = 0; s < 8; ++s) bt[s] = jac2(x0[s], x1[s]);
      if ((ii & 3) == 3) renorm(bt);
    }
  }
}

// ---------------- prep: de-interleave + transpose + scale to log2 domain --
__global__ __launch_bounds__(256) void k_prep1(const float* __restrict__ inp,
                                               float* __restrict__ ls1,
                                               float* __restrict__ gx1,
                                               float* __restrict__ gy1,
                                               float* __restrict__ gy2) {
  __shared__ float t[3][64][65];
  const int tid = threadIdx.x;
  const int k0 = blockIdx.x * 64, b0 = blockIdx.y * 64;
  const int tk = tid & 63, tq = tid >> 6;
  for (int bb = tq; bb < 64; bb += 4) {
    size_t base = (size_t)(b0 + bb) * (3 * K_) + 3 * (size_t)(k0 + tk);
    t[0][bb][tk] = inp[base + 0];
    t[1][bb][tk] = inp[base + 1];
    t[2][bb][tk] = inp[base + 2];
  }
  __syncthreads();
  const int tb = tid & 63, kq = tid >> 6;
  for (int kk = kq; kk < 64; kk += 4) {
    size_t o = (size_t)(k0 + kk) * B_ + (b0 + tb);
    float sv = -LOG2E * t[0][tb][kk];
    float p1 = -LOG2E * t[1][tb][kk];
    float p2 = -LOG2E * t[2][tb][kk];
    ls1[o] = sv;
    gx1[o] = sv;          // la=0 initially -> lsu = ls
    gy1[o] = p1;
    gy2[o] = p2;
  }
}

__global__ __launch_bounds__(256) void k_prep2(const float* __restrict__ ls1,
                                               const int* __restrict__ perm,
                                               float* __restrict__ ls2,
                                               int* __restrict__ inv) {
  const int j = blockIdx.x;
  const int b = threadIdx.x;
  const int p = perm[j];
  ls2[(size_t)j * B_ + b] = ls1[(size_t)p * B_ + b];
  if (b == 0) inv[p] = j;
}

// ---------------- output: out[b,i] = -ln2 * lpost2'[inv[i], b] ------------
__global__ __launch_bounds__(256) void k_out(const float* __restrict__ lpost2t,
                                             const int* __restrict__ inv,
                                             float* __restrict__ out) {
  __shared__ float t[64][65];
  const int tid = threadIdx.x;
  const int i0 = blockIdx.x * 64, b0 = blockIdx.y * 64;
  const int tb = tid & 63, iq = tid >> 6;
  for (int ii = iq; ii < 64; ii += 4) {
    int row = inv[i0 + ii];
    t[ii][tb] = lpost2t[(size_t)row * B_ + (b0 + tb)];
  }
  __syncthreads();
  const int ik = tid & 63, bq = tid >> 6;
  for (int bb = bq; bb < 64; bb += 4) {
    out[(size_t)(b0 + bb) * K_ + (i0 + ik)] = -LN2 * t[ik][bb];
  }
}

// ---------------- launch ---------------------------------------------------
extern "C" void kernel_launch(void* const* d_in, const int* in_sizes, int n_in,
                              void* d_out, int out_size, void* d_ws, size_t ws_size,
                              hipStream_t stream) {
  (void)in_sizes; (void)n_in; (void)out_size; (void)ws_size;
  const float* inp = (const float*)d_in[0];
  const int* perm = (const int*)d_in[1];
  float* out = (float*)d_out;

  char* ws = (char*)d_ws;
  const size_t KB = (size_t)K_ * B_;     // elements per [K][B] plane
  const size_t PB = KB * 4;              // bytes per f32 plane
  float*  gx1     = (float*)(ws);
  float*  gy1     = (float*)(ws + PB);
  float*  gx2     = (float*)(ws + PB * 2);
  float*  gy2     = (float*)(ws + PB * 3);
  float*  ls1     = (float*)(ws + PB * 4);
  float*  ls2     = (float*)(ws + PB * 5);
  float*  lpost2t = (float*)(ws + PB * 6);
  int*    inv     = (int*)(ws + PB * 7);        // K ints
  // total: 7 planes * 6 MB + 24 KB ~= 44 MB

  k_prep1<<<dim3(K_ / 64, B_ / 64), 256, 0, stream>>>(inp, ls1, gx1, gy1, gy2);
  k_prep2<<<K_, 256, 0, stream>>>(ls1, perm, ls2, inv);

  for (int it = 0; it < NITER; ++it) {
    k_half<<<C_ * 4, 64, 0, stream>>>(gx1, gy1, ls2, inv, gx2, lpost2t, 0);
    k_half<<<C_ * 4, 64, 0, stream>>>(gx2, gy2, ls1, perm, gx1, lpost2t,
                                      (it == NITER - 1) ? 1 : 0);
  }
  k_out<<<dim3(K_ / 64, B_ / 64), 256, 0, stream>>>(lpost2t, inv, out);
}

// Round 4
// 467.918 us; speedup vs baseline: 3.1806x; 1.3654x over previous
//
#include <hip/hip_runtime.h>

// ---------------- problem constants ----------------
constexpr int B_ = 256;        // batch
constexpr int K_ = 6144;       // block length
constexpr int NITER = 6;
constexpr int L_ = 12;         // window valid length -> C_*4 = 2048 waves = 2/SIMD
constexpr int W_ = 12;         // NII warmup (iterations > 0)
constexpr int W0_ = 36;        // uniform-init warmup (iteration 0)
constexpr int C_ = K_ / L_;    // chunks = 512
constexpr float NEGF = -1e30f;
constexpr float LOG2E = 1.4426950408889634f;
constexpr float LN2   = 0.6931471805599453f;

static_assert(K_ % L_ == 0, "");
static_assert((W_ % 4) == 0 && (W0_ % 4) == 0 && (L_ % 4) == 0, "");

#if __has_builtin(__builtin_amdgcn_exp2f)
#define EXP2F(x) __builtin_amdgcn_exp2f(x)
#else
#define EXP2F(x) exp2f(x)
#endif
#if __has_builtin(__builtin_amdgcn_logf)
#define LOG2F(x) __builtin_amdgcn_logf(x)
#else
#define LOG2F(x) log2f(x)
#endif

// trellis: fb(s,u)=u^s1^s0, nxt(s,u)=(fb<<2)|(s>>1), par(s,u)=u^s1^s2
// log2-domain gamma: gt[u][p] from hs=0.5*lsu', hp=0.5*lp'

__device__ __forceinline__ float jac2(float x, float y) {
  float m = fmaxf(x, y);
  float d = -fabsf(x - y);
  return m + LOG2F(1.0f + EXP2F(d));   // log2-domain Jacobian logsumexp
}

__device__ __forceinline__ void mk_gt(float gx, float gy, float gt[2][2]) {
  float hs = 0.5f * gx, hp = 0.5f * gy;
  gt[0][0] = hs + hp;
  gt[0][1] = hs - hp;
  gt[1][0] = -(hs - hp);
  gt[1][1] = -(hs + hp);
}

__device__ __forceinline__ void step_fwd(float a[8], float gx, float gy) {
  float gt[2][2];
  mk_gt(gx, gy, gt);
  float an[8];
#pragma unroll
  for (int sn = 0; sn < 8; ++sn) {
    const int u0 = ((sn >> 2) ^ (sn & 1)) & 1;
    const int p0 = ((sn >> 2) ^ ((sn >> 1) & 1)) & 1;
    float x0 = a[(sn & 3) * 2 + 0] + gt[u0][p0];
    float x1 = a[(sn & 3) * 2 + 1] + gt[u0 ^ 1][p0 ^ 1];
    an[sn] = jac2(x0, x1);
  }
#pragma unroll
  for (int s = 0; s < 8; ++s) a[s] = an[s];
}

__device__ __forceinline__ void step_bwd(float a[8], float gx, float gy) {
  float gt[2][2];
  mk_gt(gx, gy, gt);
  float an[8];
#pragma unroll
  for (int s = 0; s < 8; ++s) {
    const int s0 = s & 1, s1b = (s >> 1) & 1, s2b = (s >> 2) & 1;
    const int f0 = s1b ^ s0;
    float x0 = a[(f0 << 2) | (s >> 1)]       + gt[0][s1b ^ s2b];
    float x1 = a[((f0 ^ 1) << 2) | (s >> 1)] + gt[1][(s1b ^ s2b) ^ 1];
    an[s] = jac2(x0, x1);
  }
#pragma unroll
  for (int s = 0; s < 8; ++s) a[s] = an[s];
}

__device__ __forceinline__ void renorm(float a[8]) {
  float m = a[0];
#pragma unroll
  for (int s = 1; s < 8; ++s) a[s] -= m;
  a[0] = 0.0f;
}

// ---------------- k_half: one windowed BCJR half-iteration w/ NII ---------
// One wave per (b-quarter, chunk). alpha of the L valid positions in regs.
// Sread/Tread: boundary alpha/beta states from the PREVIOUS iteration of the
// same decoder (ping-pong; never aliased with Swrite/Twrite).
// S layout: [c][b][8] f32, c in [0, C_]; S[c] = alpha at position c*L.
// T layout: same; T[c] = beta at position c*L.
__global__ __launch_bounds__(64, 2) void k_half(const float* __restrict__ gx,
                                                const float* __restrict__ gy,
                                                const float* __restrict__ lsother,
                                                const int* __restrict__ map,
                                                float* __restrict__ gxother,
                                                float* __restrict__ lpost_out,
                                                const float* __restrict__ Sread,
                                                float* __restrict__ Swrite,
                                                const float* __restrict__ Tread,
                                                float* __restrict__ Twrite,
                                                int first, int mode) {
  const int tid = threadIdx.x;
  const unsigned wg = blockIdx.x;
  const int b = (int)(wg & 3u) * 64 + tid;
  const int c = (int)(wg >> 2);
  const int kv = c * L_;
  const int kend = kv + L_;

  // prefetch valid-region gamma (in flight during fwd warmup)
  float gvx[L_], gvy[L_];
#pragma unroll
  for (int i = 0; i < L_; ++i) {
    size_t o = (size_t)(kv + i) * B_ + b;
    gvx[i] = gx[o];
    gvy[i] = gy[o];
  }

  // ---------------- forward ----------------
  float a[8];
  int wu;                            // warmup steps (multiple of 4)
  if (c == 0) {
    wu = 0;
    a[0] = 0.0f;
#pragma unroll
    for (int s = 1; s < 8; ++s) a[s] = NEGF;
  } else if (first) {
    wu = kv < W0_ ? kv : W0_;
    if (kv <= W0_) {                 // warmup starts at position 0: exact init
      a[0] = 0.0f;
#pragma unroll
      for (int s = 1; s < 8; ++s) a[s] = NEGF;
    } else {
#pragma unroll
      for (int s = 0; s < 8; ++s) a[s] = 0.0f;
    }
  } else {
    wu = W_;
    if (c == 1) {                    // warmup starts at position 0: exact init
      a[0] = 0.0f;
#pragma unroll
      for (int s = 1; s < 8; ++s) a[s] = NEGF;
    } else {                         // NII: prev-iteration alpha at kv - W_
      const float4* rp = (const float4*)&Sread[((size_t)(c - 1) * B_ + b) * 8];
      float4 r0 = rp[0], r1 = rp[1];
      a[0] = r0.x; a[1] = r0.y; a[2] = r0.z; a[3] = r0.w;
      a[4] = r1.x; a[5] = r1.y; a[6] = r1.z; a[7] = r1.w;
    }
  }
  {
    int n = wu;
    int k = kv - wu;
    float cx[4], cy[4];
    if (n > 0) {
#pragma unroll
      for (int q = 0; q < 4; ++q) {
        size_t o = (size_t)(k + q) * B_ + b;
        cx[q] = gx[o]; cy[q] = gy[o];
      }
    }
    while (n > 0) {
      float nx[4], ny[4];
      if (n > 4) {
#pragma unroll
        for (int q = 0; q < 4; ++q) {
          size_t o = (size_t)(k + 4 + q) * B_ + b;
          nx[q] = gx[o]; ny[q] = gy[o];
        }
      }
#pragma unroll
      for (int q = 0; q < 4; ++q) step_fwd(a, cx[q], cy[q]);
      renorm(a);
      if (n > 4) {
#pragma unroll
        for (int q = 0; q < 4; ++q) { cx[q] = nx[q]; cy[q] = ny[q]; }
      }
      k += 4; n -= 4;
    }
  }
  // valid region: record alpha, then step (all L steps -> a = alpha(kend))
  float a2d[L_][8];
#pragma unroll
  for (int i = 0; i < L_; ++i) {
#pragma unroll
    for (int s = 0; s < 8; ++s) a2d[i][s] = a[s];
    step_fwd(a, gvx[i], gvy[i]);
    if ((i & 3) == 3) renorm(a);
  }
  // NII store: alpha at boundary c+1
  {
    float4* sp = (float4*)&Swrite[((size_t)(c + 1) * B_ + b) * 8];
    sp[0] = make_float4(a[0], a[1], a[2], a[3]);
    sp[1] = make_float4(a[4], a[5], a[6], a[7]);
  }

  // ---------------- backward + posterior ----------------
  float bt[8];
  int wub;
  if (c == C_ - 1) {
    wub = 0;
#pragma unroll
    for (int s = 0; s < 8; ++s) bt[s] = 0.0f;  // exact tail init
  } else if (first) {
    int rem = K_ - kend;
    wub = rem < W0_ ? rem : W0_;
#pragma unroll
    for (int s = 0; s < 8; ++s) bt[s] = 0.0f;  // uniform (exact if start==K_)
  } else {
    wub = W_;
    if (c == C_ - 2) {                         // warmup starts at K_: exact
#pragma unroll
      for (int s = 0; s < 8; ++s) bt[s] = 0.0f;
    } else {                                   // NII: prev-iter beta at kend+W_
      const float4* rp = (const float4*)&Tread[((size_t)(c + 2) * B_ + b) * 8];
      float4 r0 = rp[0], r1 = rp[1];
      bt[0] = r0.x; bt[1] = r0.y; bt[2] = r0.z; bt[3] = r0.w;
      bt[4] = r1.x; bt[5] = r1.y; bt[6] = r1.z; bt[7] = r1.w;
    }
  }
  {
    int n = wub;
    int k = kend + wub - 1;
    float cx[4], cy[4];
    if (n > 0) {
#pragma unroll
      for (int q = 0; q < 4; ++q) {
        size_t o = (size_t)(k - q) * B_ + b;
        cx[q] = gx[o]; cy[q] = gy[o];
      }
    }
    while (n > 0) {
      float nx[4], ny[4];
      if (n > 4) {
#pragma unroll
        for (int q = 0; q < 4; ++q) {
          size_t o = (size_t)(k - 4 - q) * B_ + b;
          nx[q] = gx[o]; ny[q] = gy[o];
        }
      }
#pragma unroll
      for (int q = 0; q < 4; ++q) step_bwd(bt, cx[q], cy[q]);
      renorm(bt);
      if (n > 4) {
#pragma unroll
        for (int q = 0; q < 4; ++q) { cx[q] = nx[q]; cy[q] = ny[q]; }
      }
      k -= 4; n -= 4;
    }
  }
  // valid region, descending: posterior + extrinsic + beta step (all L steps)
#pragma unroll
  for (int ii = 0; ii < L_; ++ii) {
    const int i = L_ - 1 - ii;
    const int kk = kv + i;
    float gt[2][2];
    mk_gt(gvx[i], gvy[i], gt);
    float x0[8], x1[8];
#pragma unroll
    for (int s = 0; s < 8; ++s) {
      const int s0 = s & 1, s1b = (s >> 1) & 1, s2b = (s >> 2) & 1;
      const int f0 = s1b ^ s0;
      const int p0 = s1b ^ s2b;
      x0[s] = bt[(f0 << 2) | (s >> 1)]       + gt[0][p0];
      x1[s] = bt[((f0 ^ 1) << 2) | (s >> 1)] + gt[1][p0 ^ 1];
    }
    float t0[8], t1[8];
#pragma unroll
    for (int s = 0; s < 8; ++s) {
      t0[s] = a2d[i][s] + x0[s];
      t1[s] = a2d[i][s] + x1[s];
    }
    float e0 = jac2(jac2(jac2(t0[0], t0[1]), jac2(t0[2], t0[3])),
                    jac2(jac2(t0[4], t0[5]), jac2(t0[6], t0[7])));
    float e1 = jac2(jac2(jac2(t1[0], t1[1]), jac2(t1[2], t1[3])),
                    jac2(jac2(t1[4], t1[5]), jac2(t1[6], t1[7])));
    float lpost = e0 - e1;
    if (mode == 0) {
      float le = lpost - gvx[i];               // lpost - (ls + la)
      const int j = map[kk];
      const size_t oo = (size_t)j * B_ + b;
      gxother[oo] = lsother[oo] + le;
    } else {
      lpost_out[(size_t)kk * B_ + b] = lpost;
    }
    // beta step (shares x0/x1); after last -> bt = beta(kv)
#pragma unroll
    for (int s = 0; s < 8; ++s) bt[s] = jac2(x0[s], x1[s]);
    if ((ii & 3) == 3) renorm(bt);
  }
  // NII store: beta at boundary c
  {
    float4* tp = (float4*)&Twrite[((size_t)c * B_ + b) * 8];
    tp[0] = make_float4(bt[0], bt[1], bt[2], bt[3]);
    tp[1] = make_float4(bt[4], bt[5], bt[6], bt[7]);
  }
}

// ---------------- prep: de-interleave + transpose + scale to log2 domain --
__global__ __launch_bounds__(256) void k_prep1(const float* __restrict__ inp,
                                               float* __restrict__ ls1,
                                               float* __restrict__ gx1,
                                               float* __restrict__ gy1,
                                               float* __restrict__ gy2) {
  __shared__ float t[3][64][65];
  const int tid = threadIdx.x;
  const int k0 = blockIdx.x * 64, b0 = blockIdx.y * 64;
  const int tk = tid & 63, tq = tid >> 6;
  for (int bb = tq; bb < 64; bb += 4) {
    size_t base = (size_t)(b0 + bb) * (3 * K_) + 3 * (size_t)(k0 + tk);
    t[0][bb][tk] = inp[base + 0];
    t[1][bb][tk] = inp[base + 1];
    t[2][bb][tk] = inp[base + 2];
  }
  __syncthreads();
  const int tb = tid & 63, kq = tid >> 6;
  for (int kk = kq; kk < 64; kk += 4) {
    size_t o = (size_t)(k0 + kk) * B_ + (b0 + tb);
    float sv = -LOG2E * t[0][tb][kk];
    float p1 = -LOG2E * t[1][tb][kk];
    float p2 = -LOG2E * t[2][tb][kk];
    ls1[o] = sv;
    gx1[o] = sv;          // la=0 initially -> lsu = ls
    gy1[o] = p1;
    gy2[o] = p2;
  }
}

__global__ __launch_bounds__(256) void k_prep2(const float* __restrict__ ls1,
                                               const int* __restrict__ perm,
                                               float* __restrict__ ls2,
                                               int* __restrict__ inv) {
  const int j = blockIdx.x;
  const int b = threadIdx.x;
  const int p = perm[j];
  ls2[(size_t)j * B_ + b] = ls1[(size_t)p * B_ + b];
  if (b == 0) inv[p] = j;
}

// ---------------- output: out[b,i] = -ln2 * lpost2'[inv[i], b] ------------
__global__ __launch_bounds__(256) void k_out(const float* __restrict__ lpost2t,
                                             const int* __restrict__ inv,
                                             float* __restrict__ out) {
  __shared__ float t[64][65];
  const int tid = threadIdx.x;
  const int i0 = blockIdx.x * 64, b0 = blockIdx.y * 64;
  const int tb = tid & 63, iq = tid >> 6;
  for (int ii = iq; ii < 64; ii += 4) {
    int row = inv[i0 + ii];
    t[ii][tb] = lpost2t[(size_t)row * B_ + (b0 + tb)];
  }
  __syncthreads();
  const int ik = tid & 63, bq = tid >> 6;
  for (int bb = bq; bb < 64; bb += 4) {
    out[(size_t)(b0 + bb) * K_ + (i0 + ik)] = -LN2 * t[ik][bb];
  }
}

// ---------------- launch ---------------------------------------------------
extern "C" void kernel_launch(void* const* d_in, const int* in_sizes, int n_in,
                              void* d_out, int out_size, void* d_ws, size_t ws_size,
                              hipStream_t stream) {
  (void)in_sizes; (void)n_in; (void)out_size; (void)ws_size;
  const float* inp = (const float*)d_in[0];
  const int* perm = (const int*)d_in[1];
  float* out = (float*)d_out;

  char* ws = (char*)d_ws;
  const size_t KB = (size_t)K_ * B_;     // elements per [K][B] plane
  const size_t PB = KB * 4;              // bytes per f32 plane
  float*  gx1     = (float*)(ws);
  float*  gy1     = (float*)(ws + PB);
  float*  gx2     = (float*)(ws + PB * 2);
  float*  gy2     = (float*)(ws + PB * 3);
  float*  ls1     = (float*)(ws + PB * 4);
  float*  ls2     = (float*)(ws + PB * 5);
  float*  lpost2t = (float*)(ws + PB * 6);
  int*    inv     = (int*)(ws + PB * 7);        // K ints
  // NII boundary-state buffers: [C_+1][B][8] f32, ping-pong per decoder/dir
  const size_t SB = (size_t)(C_ + 1) * B_ * 8 * 4;   // ~4.2 MB each
  char* nb = ws + PB * 8;
  float* S1[2] = {(float*)(nb),          (float*)(nb + SB)};
  float* T1[2] = {(float*)(nb + SB * 2), (float*)(nb + SB * 3)};
  float* S2[2] = {(float*)(nb + SB * 4), (float*)(nb + SB * 5)};
  float* T2[2] = {(float*)(nb + SB * 6), (float*)(nb + SB * 7)};
  // total: 8 planes * 6 MB + 8 * 4.2 MB ~= 82 MB

  k_prep1<<<dim3(K_ / 64, B_ / 64), 256, 0, stream>>>(inp, ls1, gx1, gy1, gy2);
  k_prep2<<<K_, 256, 0, stream>>>(ls1, perm, ls2, inv);

  for (int it = 0; it < NITER; ++it) {
    const int pr = it & 1, pw = pr ^ 1;   // read prev-iter buffer, write other
    k_half<<<C_ * 4, 64, 0, stream>>>(gx1, gy1, ls2, inv, gx2, lpost2t,
                                      S1[pr], S1[pw], T1[pr], T1[pw],
                                      it == 0 ? 1 : 0, 0);
    k_half<<<C_ * 4, 64, 0, stream>>>(gx2, gy2, ls1, perm, gx1, lpost2t,
                                      S2[pr], S2[pw], T2[pr], T2[pw],
                                      it == 0 ? 1 : 0,
                                      (it == NITER - 1) ? 1 : 0);
  }
  k_out<<<dim3(K_ / 64, B_ / 64), 256, 0, stream>>>(lpost2t, inv, out);
}

// Round 5
// 443.051 us; speedup vs baseline: 3.3591x; 1.0561x over previous
//
#include <hip/hip_runtime.h>

// ---------------- problem constants ----------------
constexpr int B_ = 256;        // batch
constexpr int K_ = 6144;       // block length
constexpr int NITER = 6;
constexpr int L_ = 8;          // window valid length -> C_*4 = 3072 waves = 3/SIMD
constexpr int W0_ = 32;        // uniform-init warmup (iteration 0)
constexpr int C_ = K_ / L_;    // chunks = 768
constexpr float NEGF = -1e30f;
constexpr float LOG2E = 1.4426950408889634f;
constexpr float LN2   = 0.6931471805599453f;

static_assert(K_ % L_ == 0, "");
static_assert((W0_ % 4) == 0 && (L_ % 4) == 0, "");

#if __has_builtin(__builtin_amdgcn_exp2f)
#define EXP2F(x) __builtin_amdgcn_exp2f(x)
#else
#define EXP2F(x) exp2f(x)
#endif
#if __has_builtin(__builtin_amdgcn_logf)
#define LOG2F(x) __builtin_amdgcn_logf(x)
#else
#define LOG2F(x) log2f(x)
#endif

// trellis: fb(s,u)=u^s1^s0, nxt(s,u)=(fb<<2)|(s>>1), par(s,u)=u^s1^s2
// log2-domain gamma: gt[u][p] from hs=0.5*lsu', hp=0.5*lp'

__device__ __forceinline__ float jac2(float x, float y) {
  float m = fmaxf(x, y);
  float d = -fabsf(x - y);
  return m + LOG2F(1.0f + EXP2F(d));   // log2-domain Jacobian logsumexp
}

__device__ __forceinline__ void mk_gt(float gx, float gy, float gt[2][2]) {
  float hs = 0.5f * gx, hp = 0.5f * gy;
  gt[0][0] = hs + hp;
  gt[0][1] = hs - hp;
  gt[1][0] = -(hs - hp);
  gt[1][1] = -(hs + hp);
}

__device__ __forceinline__ void step_fwd(float a[8], float gx, float gy) {
  float gt[2][2];
  mk_gt(gx, gy, gt);
  float an[8];
#pragma unroll
  for (int sn = 0; sn < 8; ++sn) {
    const int u0 = ((sn >> 2) ^ (sn & 1)) & 1;
    const int p0 = ((sn >> 2) ^ ((sn >> 1) & 1)) & 1;
    float x0 = a[(sn & 3) * 2 + 0] + gt[u0][p0];
    float x1 = a[(sn & 3) * 2 + 1] + gt[u0 ^ 1][p0 ^ 1];
    an[sn] = jac2(x0, x1);
  }
#pragma unroll
  for (int s = 0; s < 8; ++s) a[s] = an[s];
}

__device__ __forceinline__ void step_bwd(float a[8], float gx, float gy) {
  float gt[2][2];
  mk_gt(gx, gy, gt);
  float an[8];
#pragma unroll
  for (int s = 0; s < 8; ++s) {
    const int s0 = s & 1, s1b = (s >> 1) & 1, s2b = (s >> 2) & 1;
    const int f0 = s1b ^ s0;
    float x0 = a[(f0 << 2) | (s >> 1)]       + gt[0][s1b ^ s2b];
    float x1 = a[((f0 ^ 1) << 2) | (s >> 1)] + gt[1][(s1b ^ s2b) ^ 1];
    an[s] = jac2(x0, x1);
  }
#pragma unroll
  for (int s = 0; s < 8; ++s) a[s] = an[s];
}

__device__ __forceinline__ void renorm(float a[8]) {
  float m = a[0];
#pragma unroll
  for (int s = 1; s < 8; ++s) a[s] -= m;
  a[0] = 0.0f;
}

__device__ __forceinline__ void load8(const float* p, float a[8]) {
  const float4* rp = (const float4*)p;
  float4 r0 = rp[0], r1 = rp[1];
  a[0] = r0.x; a[1] = r0.y; a[2] = r0.z; a[3] = r0.w;
  a[4] = r1.x; a[5] = r1.y; a[6] = r1.z; a[7] = r1.w;
}

__device__ __forceinline__ void store8(float* p, const float a[8]) {
  float4* sp = (float4*)p;
  sp[0] = make_float4(a[0], a[1], a[2], a[3]);
  sp[1] = make_float4(a[4], a[5], a[6], a[7]);
}

// ---------------- k_half: one windowed BCJR half-iteration ----------------
// One wave per (b-quarter, chunk). alpha of the L valid positions in regs.
// wmode 0: uniform warmup W0 (iteration 0)
// wmode 1: NII — init from prev-iter boundary state + L warmup steps
// wmode 2: pure inheritance — init from prev-iter boundary state, no warmup
// S layout: [c][b][8] f32, c in [0, C_]; S[c] = alpha at position c*L_.
// T layout: same; T[c] = beta at position c*L_.
// mode 0: scatter extrinsic into other decoder's gx.  mode 1: write lpost.
__global__ __launch_bounds__(64, 3) void k_half(const float* __restrict__ gx,
                                                const float* __restrict__ gy,
                                                const float* __restrict__ lsother,
                                                const int* __restrict__ map,
                                                float* __restrict__ gxother,
                                                float* __restrict__ lpost_out,
                                                const float* __restrict__ Sread,
                                                float* __restrict__ Swrite,
                                                const float* __restrict__ Tread,
                                                float* __restrict__ Twrite,
                                                int wmode, int mode) {
  const int tid = threadIdx.x;
  const unsigned wg = blockIdx.x;
  const int b = (int)(wg & 3u) * 64 + tid;
  const int c = (int)(wg >> 2);
  const int kv = c * L_;
  const int kend = kv + L_;

  // prefetch valid-region gamma (in flight during fwd warmup)
  float gvx[L_], gvy[L_];
#pragma unroll
  for (int i = 0; i < L_; ++i) {
    size_t o = (size_t)(kv + i) * B_ + b;
    gvx[i] = gx[o];
    gvy[i] = gy[o];
  }

  // ---------------- forward ----------------
  float a[8];
  int wu;                            // warmup steps (multiple of 4)
  if (c == 0) {
    wu = 0;
    a[0] = 0.0f;
#pragma unroll
    for (int s = 1; s < 8; ++s) a[s] = NEGF;
  } else if (wmode == 0) {
    wu = kv < W0_ ? kv : W0_;
    if (kv <= W0_) {                 // warmup starts at position 0: exact init
      a[0] = 0.0f;
#pragma unroll
      for (int s = 1; s < 8; ++s) a[s] = NEGF;
    } else {
#pragma unroll
      for (int s = 0; s < 8; ++s) a[s] = 0.0f;
    }
  } else if (wmode == 1) {
    wu = L_;
    if (c == 1) {                    // warmup starts at position 0: exact init
      a[0] = 0.0f;
#pragma unroll
      for (int s = 1; s < 8; ++s) a[s] = NEGF;
    } else {                         // NII: prev-iteration alpha at kv - L_
      load8(&Sread[((size_t)(c - 1) * B_ + b) * 8], a);
    }
  } else {
    wu = 0;                          // pure inheritance: alpha at kv
    load8(&Sread[((size_t)c * B_ + b) * 8], a);
  }
  {
    int n = wu;
    int k = kv - wu;
    float cx[4], cy[4];
    if (n > 0) {
#pragma unroll
      for (int q = 0; q < 4; ++q) {
        size_t o = (size_t)(k + q) * B_ + b;
        cx[q] = gx[o]; cy[q] = gy[o];
      }
    }
    while (n > 0) {
      float nx[4], ny[4];
      if (n > 4) {
#pragma unroll
        for (int q = 0; q < 4; ++q) {
          size_t o = (size_t)(k + 4 + q) * B_ + b;
          nx[q] = gx[o]; ny[q] = gy[o];
        }
      }
#pragma unroll
      for (int q = 0; q < 4; ++q) step_fwd(a, cx[q], cy[q]);
      renorm(a);
      if (n > 4) {
#pragma unroll
        for (int q = 0; q < 4; ++q) { cx[q] = nx[q]; cy[q] = ny[q]; }
      }
      k += 4; n -= 4;
    }
  }
  // valid region: record alpha, then step (all L steps -> a = alpha(kend))
  float a2d[L_][8];
#pragma unroll
  for (int i = 0; i < L_; ++i) {
#pragma unroll
    for (int s = 0; s < 8; ++s) a2d[i][s] = a[s];
    step_fwd(a, gvx[i], gvy[i]);
    if ((i & 3) == 3) renorm(a);
  }
  // NII store: alpha at boundary c+1
  store8(&Swrite[((size_t)(c + 1) * B_ + b) * 8], a);

  // ---------------- backward + posterior ----------------
  float bt[8];
  int wub;
  if (c == C_ - 1) {
    wub = 0;
#pragma unroll
    for (int s = 0; s < 8; ++s) bt[s] = 0.0f;  // exact tail init
  } else if (wmode == 0) {
    int rem = K_ - kend;
    wub = rem < W0_ ? rem : W0_;
#pragma unroll
    for (int s = 0; s < 8; ++s) bt[s] = 0.0f;  // uniform (exact if start==K_)
  } else if (wmode == 1) {
    wub = L_;
    if (c == C_ - 2) {                         // warmup starts at K_: exact
#pragma unroll
      for (int s = 0; s < 8; ++s) bt[s] = 0.0f;
    } else {                                   // NII: prev-iter beta at kend+L_
      load8(&Tread[((size_t)(c + 2) * B_ + b) * 8], bt);
    }
  } else {
    wub = 0;                                   // pure inheritance: beta at kend
    load8(&Tread[((size_t)(c + 1) * B_ + b) * 8], bt);
  }
  {
    int n = wub;
    int k = kend + wub - 1;
    float cx[4], cy[4];
    if (n > 0) {
#pragma unroll
      for (int q = 0; q < 4; ++q) {
        size_t o = (size_t)(k - q) * B_ + b;
        cx[q] = gx[o]; cy[q] = gy[o];
      }
    }
    while (n > 0) {
      float nx[4], ny[4];
      if (n > 4) {
#pragma unroll
        for (int q = 0; q < 4; ++q) {
          size_t o = (size_t)(k - 4 - q) * B_ + b;
          nx[q] = gx[o]; ny[q] = gy[o];
        }
      }
#pragma unroll
      for (int q = 0; q < 4; ++q) step_bwd(bt, cx[q], cy[q]);
      renorm(bt);
      if (n > 4) {
#pragma unroll
        for (int q = 0; q < 4; ++q) { cx[q] = nx[q]; cy[q] = ny[q]; }
      }
      k -= 4; n -= 4;
    }
  }
  // valid region, descending: posterior + extrinsic + beta step (all L steps)
#pragma unroll
  for (int ii = 0; ii < L_; ++ii) {
    const int i = L_ - 1 - ii;
    const int kk = kv + i;
    float gt[2][2];
    mk_gt(gvx[i], gvy[i], gt);
    float x0[8], x1[8];
#pragma unroll
    for (int s = 0; s < 8; ++s) {
      const int s0 = s & 1, s1b = (s >> 1) & 1, s2b = (s >> 2) & 1;
      const int f0 = s1b ^ s0;
      const int p0 = s1b ^ s2b;
      x0[s] = bt[(f0 << 2) | (s >> 1)]       + gt[0][p0];
      x1[s] = bt[((f0 ^ 1) << 2) | (s >> 1)] + gt[1][p0 ^ 1];
    }
    float t0[8], t1[8];
#pragma unroll
    for (int s = 0; s < 8; ++s) {
      t0[s] = a2d[i][s] + x0[s];
      t1[s] = a2d[i][s] + x1[s];
    }
    float e0 = jac2(jac2(jac2(t0[0], t0[1]), jac2(t0[2], t0[3])),
                    jac2(jac2(t0[4], t0[5]), jac2(t0[6], t0[7])));
    float e1 = jac2(jac2(jac2(t1[0], t1[1]), jac2(t1[2], t1[3])),
                    jac2(jac2(t1[4], t1[5]), jac2(t1[6], t1[7])));
    float lpost = e0 - e1;
    if (mode == 0) {
      float le = lpost - gvx[i];               // lpost - (ls + la)
      const int j = map[kk];
      const size_t oo = (size_t)j * B_ + b;
      gxother[oo] = lsother[oo] + le;
    } else {
      lpost_out[(size_t)kk * B_ + b] = lpost;
    }
    // beta step (shares x0/x1); after last -> bt = beta(kv)
#pragma unroll
    for (int s = 0; s < 8; ++s) bt[s] = jac2(x0[s], x1[s]);
    if ((ii & 3) == 3) renorm(bt);
  }
  // NII store: beta at boundary c
  store8(&Twrite[((size_t)c * B_ + b) * 8], bt);
}

// ---------------- prep: de-interleave + transpose + scale to log2 domain --
__global__ __launch_bounds__(256) void k_prep1(const float* __restrict__ inp,
                                               float* __restrict__ ls1,
                                               float* __restrict__ gx1,
                                               float* __restrict__ gy1,
                                               float* __restrict__ gy2) {
  __shared__ float t[3][64][65];
  const int tid = threadIdx.x;
  const int k0 = blockIdx.x * 64, b0 = blockIdx.y * 64;
  const int tk = tid & 63, tq = tid >> 6;
  for (int bb = tq; bb < 64; bb += 4) {
    size_t base = (size_t)(b0 + bb) * (3 * K_) + 3 * (size_t)(k0 + tk);
    t[0][bb][tk] = inp[base + 0];
    t[1][bb][tk] = inp[base + 1];
    t[2][bb][tk] = inp[base + 2];
  }
  __syncthreads();
  const int tb = tid & 63, kq = tid >> 6;
  for (int kk = kq; kk < 64; kk += 4) {
    size_t o = (size_t)(k0 + kk) * B_ + (b0 + tb);
    float sv = -LOG2E * t[0][tb][kk];
    float p1 = -LOG2E * t[1][tb][kk];
    float p2 = -LOG2E * t[2][tb][kk];
    ls1[o] = sv;
    gx1[o] = sv;          // la=0 initially -> lsu = ls
    gy1[o] = p1;
    gy2[o] = p2;
  }
}

__global__ __launch_bounds__(256) void k_prep2(const float* __restrict__ ls1,
                                               const int* __restrict__ perm,
                                               float* __restrict__ ls2,
                                               int* __restrict__ inv) {
  const int j = blockIdx.x;
  const int b = threadIdx.x;
  const int p = perm[j];
  ls2[(size_t)j * B_ + b] = ls1[(size_t)p * B_ + b];
  if (b == 0) inv[p] = j;
}

// ---------------- output: out[b,i] = -ln2 * lpost2'[inv[i], b] ------------
__global__ __launch_bounds__(256) void k_out(const float* __restrict__ lpost2t,
                                             const int* __restrict__ inv,
                                             float* __restrict__ out) {
  __shared__ float t[64][65];
  const int tid = threadIdx.x;
  const int i0 = blockIdx.x * 64, b0 = blockIdx.y * 64;
  const int tb = tid & 63, iq = tid >> 6;
  for (int ii = iq; ii < 64; ii += 4) {
    int row = inv[i0 + ii];
    t[ii][tb] = lpost2t[(size_t)row * B_ + (b0 + tb)];
  }
  __syncthreads();
  const int ik = tid & 63, bq = tid >> 6;
  for (int bb = bq; bb < 64; bb += 4) {
    out[(size_t)(b0 + bb) * K_ + (i0 + ik)] = -LN2 * t[ik][bb];
  }
}

// ---------------- launch ---------------------------------------------------
extern "C" void kernel_launch(void* const* d_in, const int* in_sizes, int n_in,
                              void* d_out, int out_size, void* d_ws, size_t ws_size,
                              hipStream_t stream) {
  (void)in_sizes; (void)n_in; (void)out_size; (void)ws_size;
  const float* inp = (const float*)d_in[0];
  const int* perm = (const int*)d_in[1];
  float* out = (float*)d_out;

  char* ws = (char*)d_ws;
  const size_t KB = (size_t)K_ * B_;     // elements per [K][B] plane
  const size_t PB = KB * 4;              // bytes per f32 plane
  float*  gx1     = (float*)(ws);
  float*  gy1     = (float*)(ws + PB);
  float*  gx2     = (float*)(ws + PB * 2);
  float*  gy2     = (float*)(ws + PB * 3);
  float*  ls1     = (float*)(ws + PB * 4);
  float*  ls2     = (float*)(ws + PB * 5);
  float*  lpost2t = (float*)(ws + PB * 6);
  int*    inv     = (int*)(ws + PB * 7);        // K ints
  // NII boundary-state buffers: [C_+1][B][8] f32, ping-pong per decoder/dir
  const size_t SB = (size_t)(C_ + 1) * B_ * 8 * 4;   // ~6.3 MB each
  char* nb = ws + PB * 8;
  float* S1[2] = {(float*)(nb),          (float*)(nb + SB)};
  float* T1[2] = {(float*)(nb + SB * 2), (float*)(nb + SB * 3)};
  float* S2[2] = {(float*)(nb + SB * 4), (float*)(nb + SB * 5)};
  float* T2[2] = {(float*)(nb + SB * 6), (float*)(nb + SB * 7)};
  // total: 8 planes * 6 MB + 8 * 6.3 MB ~= 98 MB

  k_prep1<<<dim3(K_ / 64, B_ / 64), 256, 0, stream>>>(inp, ls1, gx1, gy1, gy2);
  k_prep2<<<K_, 256, 0, stream>>>(ls1, perm, ls2, inv);

  for (int it = 0; it < NITER; ++it) {
    const int pr = it & 1, pw = pr ^ 1;   // read prev-iter buffer, write other
    const int wm = (it == 0) ? 0 : (it <= 3 ? 1 : 2);
    k_half<<<C_ * 4, 64, 0, stream>>>(gx1, gy1, ls2, inv, gx2, lpost2t,
                                      S1[pr], S1[pw], T1[pr], T1[pw],
                                      wm, 0);
    k_half<<<C_ * 4, 64, 0, stream>>>(gx2, gy2, ls1, perm, gx1, lpost2t,
                                      S2[pr], S2[pw], T2[pr], T2[pw],
                                      wm, (it == NITER - 1) ? 1 : 0);
  }
  k_out<<<dim3(K_ / 64, B_ / 64), 256, 0, stream>>>(lpost2t, inv, out);
}

// Round 6
// 290.767 us; speedup vs baseline: 5.1183x; 1.5237x over previous
//
#include <hip/hip_runtime.h>

// ---------------- problem constants ----------------
constexpr int B_ = 256;        // batch
constexpr int K_ = 6144;       // block length
constexpr int NITER = 6;
constexpr int L_ = 6;          // window valid length -> C_*4 = 4096 waves = 4/SIMD
constexpr int W0_ = 32;        // uniform-init warmup (iteration 0)
constexpr int C_ = K_ / L_;    // chunks = 1024
constexpr float LOG2E = 1.4426950408889634f;
constexpr float LN2   = 0.6931471805599453f;

static_assert(K_ % L_ == 0, "");
static_assert((L_ % 2) == 0 && (W0_ % 2) == 0, "");

#if __has_builtin(__builtin_amdgcn_exp2f)
#define EXP2F(x) __builtin_amdgcn_exp2f(x)
#else
#define EXP2F(x) exp2f(x)
#endif
#if __has_builtin(__builtin_amdgcn_logf)
#define LOG2F(x) __builtin_amdgcn_logf(x)
#else
#define LOG2F(x) log2f(x)
#endif
#if __has_builtin(__builtin_amdgcn_rcpf)
#define RCPF(x) __builtin_amdgcn_rcpf(x)
#else
#define RCPF(x) (1.0f / (x))
#endif

// trellis: fb(s,u)=u^s1^s0, nxt(s,u)=(fb<<2)|(s>>1), par(s,u)=u^s1^s2
// Linear-domain with normalized gammas: true gamma[u][p] = 2^(su*hs+sp*hp),
// hs=gx/2, hp=gy/2. Scaled by 2^(-|hs|-|hp|): ghat[u][p] = A_u*B_p with
// A = {1, es} by sign of gx (es = 2^-|gx|), B likewise (ep = 2^-|gy|).
// Common scale cancels in the posterior LLR ratio and in renormalized
// alpha/beta, so this is numerically equivalent to log-MAP.

// g[4] = {g00, g01, g10, g11} indexed g[u*2+p]
__device__ __forceinline__ void gam_lin(float gxv, float gyv, float g[4]) {
  float es = EXP2F(-fabsf(gxv));
  float ep = EXP2F(-fabsf(gyv));
  float fu0 = gxv >= 0.0f ? 1.0f : es;
  float fu1 = gxv >= 0.0f ? es : 1.0f;
  float fp0 = gyv >= 0.0f ? 1.0f : ep;
  float fp1 = gyv >= 0.0f ? ep : 1.0f;
  g[0] = fu0 * fp0; g[1] = fu0 * fp1;
  g[2] = fu1 * fp0; g[3] = fu1 * fp1;
}

__device__ __forceinline__ void step_fwd_lin(float a[8], const float g[4]) {
  float an[8];
#pragma unroll
  for (int sn = 0; sn < 8; ++sn) {
    const int u0 = ((sn >> 2) ^ (sn & 1)) & 1;
    const int p0 = ((sn >> 2) ^ ((sn >> 1) & 1)) & 1;
    an[sn] = a[(sn & 3) * 2] * g[u0 * 2 + p0]
           + a[(sn & 3) * 2 + 1] * g[(u0 ^ 1) * 2 + (p0 ^ 1)];
  }
#pragma unroll
  for (int s = 0; s < 8; ++s) a[s] = an[s];
}

__device__ __forceinline__ void step_bwd_lin(float bt[8], const float g[4]) {
  float bn[8];
#pragma unroll
  for (int s = 0; s < 8; ++s) {
    const int s0 = s & 1, s1b = (s >> 1) & 1, s2b = (s >> 2) & 1;
    const int f0 = s1b ^ s0, q = s1b ^ s2b;
    bn[s] = g[q] * bt[(f0 << 2) | (s >> 1)]
          + g[2 + (q ^ 1)] * bt[((f0 ^ 1) << 2) | (s >> 1)];
  }
#pragma unroll
  for (int s = 0; s < 8; ++s) bt[s] = bn[s];
}

// max-renorm with tiny floor injection: NaN/underflow-proof, floor sits at
// ~2^-106 relative (negligible vs any live path)
__device__ __forceinline__ void renorm_lin(float a[8]) {
  float m = fmaxf(fmaxf(fmaxf(a[0], a[1]), fmaxf(a[2], a[3])),
                  fmaxf(fmaxf(a[4], a[5]), fmaxf(a[6], a[7])));
  float r = RCPF(fmaxf(m, 1e-30f));
#pragma unroll
  for (int s = 0; s < 8; ++s) a[s] = fmaf(a[s], r, 1e-32f);
}

__device__ __forceinline__ void load8(const float* p, float a[8]) {
  const float4* rp = (const float4*)p;
  float4 r0 = rp[0], r1 = rp[1];
  a[0] = r0.x; a[1] = r0.y; a[2] = r0.z; a[3] = r0.w;
  a[4] = r1.x; a[5] = r1.y; a[6] = r1.z; a[7] = r1.w;
}

__device__ __forceinline__ void store8(float* p, const float a[8]) {
  float4* sp = (float4*)p;
  sp[0] = make_float4(a[0], a[1], a[2], a[3]);
  sp[1] = make_float4(a[4], a[5], a[6], a[7]);
}

// ---------------- k_half: one windowed BCJR half-iteration (linear) -------
// One wave per (b-quarter, chunk). wmode 0: uniform warmup W0 (it 0);
// wmode 1: NII boundary state + L warmup steps; wmode 2: pure inheritance.
// S[c] = alpha at position c*L_ (linear, renormed); T[c] = beta at c*L_.
// mode 0: scatter extrinsic into other decoder's gx.  mode 1: write lpost.
__global__ __launch_bounds__(64, 4) void k_half(const float* __restrict__ gx,
                                                const float* __restrict__ gy,
                                                const float* __restrict__ lsother,
                                                const int* __restrict__ map,
                                                float* __restrict__ gxother,
                                                float* __restrict__ lpost_out,
                                                const float* __restrict__ Sread,
                                                float* __restrict__ Swrite,
                                                const float* __restrict__ Tread,
                                                float* __restrict__ Twrite,
                                                int wmode, int mode) {
  const int tid = threadIdx.x;
  const unsigned wg = blockIdx.x;
  const int b = (int)(wg & 3u) * 64 + tid;
  const int c = (int)(wg >> 2);
  const int kv = c * L_;
  const int kend = kv + L_;

  // valid-region gamma: load + convert to linear scaled table (cached)
  float gvx[L_];        // log2-domain lsu (needed for extrinsic)
  float gc[L_][4];      // linear scaled gamma table
#pragma unroll
  for (int i = 0; i < L_; ++i) {
    size_t o = (size_t)(kv + i) * B_ + b;
    float x = gx[o], y = gy[o];
    gvx[i] = x;
    gam_lin(x, y, gc[i]);
  }

  // ---------------- forward ----------------
  float a[8];
  int wu;
  if (c == 0) {
    wu = 0;
    a[0] = 1.0f;
#pragma unroll
    for (int s = 1; s < 8; ++s) a[s] = 0.0f;
  } else if (wmode == 0) {
    wu = kv < W0_ ? kv : W0_;
    if (kv <= W0_) {                 // warmup reaches position 0: exact init
      a[0] = 1.0f;
#pragma unroll
      for (int s = 1; s < 8; ++s) a[s] = 0.0f;
    } else {
#pragma unroll
      for (int s = 0; s < 8; ++s) a[s] = 1.0f;
    }
  } else if (wmode == 1) {
    wu = L_;
    if (c == 1) {                    // warmup starts at position 0: exact init
      a[0] = 1.0f;
#pragma unroll
      for (int s = 1; s < 8; ++s) a[s] = 0.0f;
    } else {                         // NII: prev-iteration alpha at kv - L_
      load8(&Sread[((size_t)(c - 1) * B_ + b) * 8], a);
    }
  } else {
    wu = 0;                          // pure inheritance: alpha at kv
    load8(&Sread[((size_t)c * B_ + b) * 8], a);
  }
  {
    int n = wu;                      // always even
    int k = kv - wu;
    float cx0, cy0, cx1, cy1;
    if (n > 0) {
      size_t o0 = (size_t)k * B_ + b, o1 = (size_t)(k + 1) * B_ + b;
      cx0 = gx[o0]; cy0 = gy[o0]; cx1 = gx[o1]; cy1 = gy[o1];
    }
    while (n > 0) {
      float nx0, ny0, nx1, ny1;
      if (n > 2) {
        size_t o0 = (size_t)(k + 2) * B_ + b, o1 = (size_t)(k + 3) * B_ + b;
        nx0 = gx[o0]; ny0 = gy[o0]; nx1 = gx[o1]; ny1 = gy[o1];
      }
      float g[4];
      gam_lin(cx0, cy0, g); step_fwd_lin(a, g);
      gam_lin(cx1, cy1, g); step_fwd_lin(a, g);
      renorm_lin(a);
      if (n > 2) { cx0 = nx0; cy0 = ny0; cx1 = nx1; cy1 = ny1; }
      k += 2; n -= 2;
    }
  }
  // valid region: record alpha, then step (all L steps -> a = alpha(kend))
  float a2d[L_][8];
#pragma unroll
  for (int i = 0; i < L_; ++i) {
#pragma unroll
    for (int s = 0; s < 8; ++s) a2d[i][s] = a[s];
    step_fwd_lin(a, gc[i]);
    if (i == 2 || i == L_ - 1) renorm_lin(a);
  }
  store8(&Swrite[((size_t)(c + 1) * B_ + b) * 8], a);

  // ---------------- backward + posterior ----------------
  float bt[8];
  int wub;
  if (c == C_ - 1) {
    wub = 0;
#pragma unroll
    for (int s = 0; s < 8; ++s) bt[s] = 1.0f;  // exact tail init (uniform)
  } else if (wmode == 0) {
    int rem = K_ - kend;
    wub = rem < W0_ ? rem : W0_;
#pragma unroll
    for (int s = 0; s < 8; ++s) bt[s] = 1.0f;
  } else if (wmode == 1) {
    wub = L_;
#pragma unroll
    for (int s = 0; s < 8; ++s) bt[s] = 1.0f;
    if (c < C_ - 2) {                          // NII: prev-iter beta at kend+L_
      load8(&Tread[((size_t)(c + 2) * B_ + b) * 8], bt);
    }
  } else {
    wub = 0;                                   // pure inheritance: beta at kend
    load8(&Tread[((size_t)(c + 1) * B_ + b) * 8], bt);
  }
  {
    int n = wub;                     // always even
    int k = kend + wub - 1;
    float cx0, cy0, cx1, cy1;
    if (n > 0) {
      size_t o0 = (size_t)k * B_ + b, o1 = (size_t)(k - 1) * B_ + b;
      cx0 = gx[o0]; cy0 = gy[o0]; cx1 = gx[o1]; cy1 = gy[o1];
    }
    while (n > 0) {
      float nx0, ny0, nx1, ny1;
      if (n > 2) {
        size_t o0 = (size_t)(k - 2) * B_ + b, o1 = (size_t)(k - 3) * B_ + b;
        nx0 = gx[o0]; ny0 = gy[o0]; nx1 = gx[o1]; ny1 = gy[o1];
      }
      float g[4];
      gam_lin(cx0, cy0, g); step_bwd_lin(bt, g);
      gam_lin(cx1, cy1, g); step_bwd_lin(bt, g);
      renorm_lin(bt);
      if (n > 2) { cx0 = nx0; cy0 = ny0; cx1 = nx1; cy1 = ny1; }
      k -= 2; n -= 2;
    }
  }
  // valid region, descending: posterior + extrinsic + beta step
#pragma unroll
  for (int ii = 0; ii < L_; ++ii) {
    const int i = L_ - 1 - ii;
    const int kk = kv + i;
    const float* g = gc[i];
    float s00 = 0.0f, s01 = 0.0f, s10 = 0.0f, s11 = 0.0f;
    float bn[8];
#pragma unroll
    for (int s = 0; s < 8; ++s) {
      const int s0 = s & 1, s1b = (s >> 1) & 1, s2b = (s >> 2) & 1;
      const int f0 = s1b ^ s0, q = s1b ^ s2b;
      float b0 = bt[(f0 << 2) | (s >> 1)];
      float b1 = bt[((f0 ^ 1) << 2) | (s >> 1)];
      float m0 = a2d[i][s] * b0;
      float m1 = a2d[i][s] * b1;
      if (q == 0) { s00 += m0; s10 += m1; } else { s01 += m0; s11 += m1; }
      bn[s] = g[q] * b0 + g[2 + (q ^ 1)] * b1;
    }
    float t0 = g[0] * s00 + g[1] * s01;
    float t1 = g[3] * s10 + g[2] * s11;
    float lpost = LOG2F(fmaxf(t0, 1e-37f)) - LOG2F(fmaxf(t1, 1e-37f));
    if (mode == 0) {
      float le = lpost - gvx[i];               // lpost - (ls + la)
      const int j = map[kk];
      const size_t oo = (size_t)j * B_ + b;
      gxother[oo] = lsother[oo] + le;
    } else {
      lpost_out[(size_t)kk * B_ + b] = lpost;
    }
#pragma unroll
    for (int s = 0; s < 8; ++s) bt[s] = bn[s];
    if (ii == 2 || ii == L_ - 1) renorm_lin(bt);
  }
  store8(&Twrite[((size_t)c * B_ + b) * 8], bt);
}

// ---------------- prep: de-interleave + transpose + scale to log2 domain --
__global__ __launch_bounds__(256) void k_prep1(const float* __restrict__ inp,
                                               float* __restrict__ ls1,
                                               float* __restrict__ gx1,
                                               float* __restrict__ gy1,
                                               float* __restrict__ gy2) {
  __shared__ float t[3][64][65];
  const int tid = threadIdx.x;
  const int k0 = blockIdx.x * 64, b0 = blockIdx.y * 64;
  const int tk = tid & 63, tq = tid >> 6;
  for (int bb = tq; bb < 64; bb += 4) {
    size_t base = (size_t)(b0 + bb) * (3 * K_) + 3 * (size_t)(k0 + tk);
    t[0][bb][tk] = inp[base + 0];
    t[1][bb][tk] = inp[base + 1];
    t[2][bb][tk] = inp[base + 2];
  }
  __syncthreads();
  const int tb = tid & 63, kq = tid >> 6;
  for (int kk = kq; kk < 64; kk += 4) {
    size_t o = (size_t)(k0 + kk) * B_ + (b0 + tb);
    float sv = -LOG2E * t[0][tb][kk];
    float p1 = -LOG2E * t[1][tb][kk];
    float p2 = -LOG2E * t[2][tb][kk];
    ls1[o] = sv;
    gx1[o] = sv;          // la=0 initially -> lsu = ls
    gy1[o] = p1;
    gy2[o] = p2;
  }
}

__global__ __launch_bounds__(256) void k_prep2(const float* __restrict__ ls1,
                                               const int* __restrict__ perm,
                                               float* __restrict__ ls2,
                                               int* __restrict__ inv) {
  const int j = blockIdx.x;
  const int b = threadIdx.x;
  const int p = perm[j];
  ls2[(size_t)j * B_ + b] = ls1[(size_t)p * B_ + b];
  if (b == 0) inv[p] = j;
}

// ---------------- output: out[b,i] = -ln2 * lpost2'[inv[i], b] ------------
__global__ __launch_bounds__(256) void k_out(const float* __restrict__ lpost2t,
                                             const int* __restrict__ inv,
                                             float* __restrict__ out) {
  __shared__ float t[64][65];
  const int tid = threadIdx.x;
  const int i0 = blockIdx.x * 64, b0 = blockIdx.y * 64;
  const int tb = tid & 63, iq = tid >> 6;
  for (int ii = iq; ii < 64; ii += 4) {
    int row = inv[i0 + ii];
    t[ii][tb] = lpost2t[(size_t)row * B_ + (b0 + tb)];
  }
  __syncthreads();
  const int ik = tid & 63, bq = tid >> 6;
  for (int bb = bq; bb < 64; bb += 4) {
    out[(size_t)(b0 + bb) * K_ + (i0 + ik)] = -LN2 * t[ik][bb];
  }
}

// ---------------- launch ---------------------------------------------------
extern "C" void kernel_launch(void* const* d_in, const int* in_sizes, int n_in,
                              void* d_out, int out_size, void* d_ws, size_t ws_size,
                              hipStream_t stream) {
  (void)in_sizes; (void)n_in; (void)out_size; (void)ws_size;
  const float* inp = (const float*)d_in[0];
  const int* perm = (const int*)d_in[1];
  float* out = (float*)d_out;

  char* ws = (char*)d_ws;
  const size_t KB = (size_t)K_ * B_;     // elements per [K][B] plane
  const size_t PB = KB * 4;              // bytes per f32 plane
  float*  gx1     = (float*)(ws);
  float*  gy1     = (float*)(ws + PB);
  float*  gx2     = (float*)(ws + PB * 2);
  float*  gy2     = (float*)(ws + PB * 3);
  float*  ls1     = (float*)(ws + PB * 4);
  float*  ls2     = (float*)(ws + PB * 5);
  float*  lpost2t = (float*)(ws + PB * 6);
  int*    inv     = (int*)(ws + PB * 7);        // K ints
  // NII boundary-state buffers: [C_+1][B][8] f32, ping-pong per decoder/dir
  const size_t SB = (size_t)(C_ + 1) * B_ * 8 * 4;   // ~8.4 MB each
  char* nb = ws + PB * 8;
  float* S1[2] = {(float*)(nb),          (float*)(nb + SB)};
  float* T1[2] = {(float*)(nb + SB * 2), (float*)(nb + SB * 3)};
  float* S2[2] = {(float*)(nb + SB * 4), (float*)(nb + SB * 5)};
  float* T2[2] = {(float*)(nb + SB * 6), (float*)(nb + SB * 7)};
  // total: 8 planes * 6 MB + 8 * 8.4 MB ~= 117 MB

  k_prep1<<<dim3(K_ / 64, B_ / 64), 256, 0, stream>>>(inp, ls1, gx1, gy1, gy2);
  k_prep2<<<K_, 256, 0, stream>>>(ls1, perm, ls2, inv);

  for (int it = 0; it < NITER; ++it) {
    const int pr = it & 1, pw = pr ^ 1;   // read prev-iter buffer, write other
    const int wm = (it == 0) ? 0 : (it <= 3 ? 1 : 2);
    k_half<<<C_ * 4, 64, 0, stream>>>(gx1, gy1, ls2, inv, gx2, lpost2t,
                                      S1[pr], S1[pw], T1[pr], T1[pw],
                                      wm, 0);
    k_half<<<C_ * 4, 64, 0, stream>>>(gx2, gy2, ls1, perm, gx1, lpost2t,
                                      S2[pr], S2[pw], T2[pr], T2[pw],
                                      wm, (it == NITER - 1) ? 1 : 0);
  }
  k_out<<<dim3(K_ / 64, B_ / 64), 256, 0, stream>>>(lpost2t, inv, out);
}